// Round 3
// baseline (140.545 us; speedup 1.0000x reference)
//
#include <hip/hip_runtime.h>
#include <hip/hip_bf16.h>
#include <math.h>

// Problem dims (fixed by reference)
#define B_SZ 256
#define P_SZ 256
#define LD   128   // L_DIM (evolving part)
#define ZD   256   // Z_DIM
#define HD   256   // H_DIM
#define DPTS 128   // points per decode block (2 blocks per row)
// Integrator: single Heun step over [x0, x[255]], 2 MLP evals total; the
// Hermite right slope is k2 = f(t1, vL+H*k1) (predictor slope). Error budget
// unchanged from prior rounds; ODE now computed in f32 (strictly more
// accurate than the old bf16 MFMA path) — absmax floor stays the bf16
// quantization of the latent in decode (0.0078125).
//
// R3: R1/R2 algebra showed pack+MFMA-ode+gap ~ 18.5 us — the MFMA ODE is
// structurally stuck at 16 blocks (layer k+1 needs all of layer k), idling
// 240 CUs, and needs a pack kernel + extra launch. Replaced with a 128-block
// f32 GEMV ODE: thread j owns unit j, 2 batch rows per block (weight loads
// amortized x2), split-K on layer 3. ~4.3 us L2-BW bound / ~4.2 us issue
// bound. Pack kernel deleted (2 launches total). Decode = verified R2 form.

typedef __attribute__((ext_vector_type(8))) short short8;   // 8 bf16 = 4 VGPRs
typedef __attribute__((ext_vector_type(4))) float v4f;      // mfma C/D

__device__ __forceinline__ float fast_tanh(float v) {
  float e = __expf(2.0f * fabsf(v));
  float r = 1.0f - 2.0f / (e + 1.0f);
  return copysignf(r, v);
}

__device__ __forceinline__ unsigned int bf_bits(float f) {
  unsigned int u = __float_as_uint(f);
  return (u + 0x7fffu + ((u >> 16) & 1u)) >> 16;   // RNE
}
__device__ __forceinline__ float bf_lo(unsigned int u) {
  return __uint_as_float(u << 16);
}
__device__ __forceinline__ float bf_hi(unsigned int u) {
  return __uint_as_float(u & 0xffff0000u);
}

// Build one MFMA B-fragment in lane order: lane (col,quad) holds
// B[k = kb..kb+7][n], kb = ks*32 + quad*8, as 8 bf16 (RNE from f32).
__device__ __forceinline__ short8 pack_bfrag(const float* __restrict__ W,
                                             int stride, int kb, int n) {
  short8 r;
#pragma unroll
  for (int j = 0; j < 8; j++)
    r[j] = (short)bf_bits(W[(kb + j) * stride + n]);
  return r;
}

// ---------------------------------------------------------------------------
// Kernel 1: GEMV ODE, Heun with predictor right slope (2 evals), all f32.
// 128 blocks x 256 threads; block handles batch rows b0=2*blk, b0+1.
// Thread j owns hidden unit j; column loads W[k*HD+j] coalesced and shared
// across both rows. Layer 3 (128 outputs) split-K across thread halves.
// Writes one state slice (vL, k1, vNew, k2) per row to dstate.
// ---------------------------------------------------------------------------
__global__ __launch_bounds__(256) void ode_gemv_kernel(
    const float* __restrict__ x, const float* __restrict__ z,
    const float* __restrict__ x0,
    const float* __restrict__ W1, const float* __restrict__ b1,
    const float* __restrict__ W2, const float* __restrict__ b2,
    const float* __restrict__ W3, const float* __restrict__ b3,
    float* __restrict__ dstate)   // [256 rows][4][128] f32
{
  __shared__ __align__(16) float vLs[2][LD], zfs[2][LD], vins[2][LD];
  __shared__ __align__(16) float hA[2][HD], hB[2][HD];
  __shared__ __align__(16) float k1s[2][LD], k2s[2][LD];
  __shared__ __align__(16) float p3[2][2][LD];   // [khalf][row][unit]

  const int j  = threadIdx.x;
  const int b0 = blockIdx.x * 2;

  // stage z rows: first 128 = evolving vL, last 128 = frozen zf
#pragma unroll
  for (int r = 0; r < 2; r++) {
    float v = z[(b0 + r) * ZD + j];
    if (j < LD) vLs[r][j] = v; else zfs[r][j - LD] = v;
  }
  const float tv0 = x0[0];
  const float tv1 = x[P_SZ - 1];
  const float H   = tv1 - tv0;
  __syncthreads();

  // c1 = b1 + zf @ W1[128:256]  (t-independent part of layer 1), per row
  float c1a = b1[j], c1b = c1a;
  {
    const float4* za4 = (const float4*)zfs[0];
    const float4* zb4 = (const float4*)zfs[1];
#pragma unroll 8
    for (int k4 = 0; k4 < LD / 4; k4++) {
      float4 za = za4[k4], zb = zb4[k4];
      float zaa[4] = {za.x, za.y, za.z, za.w};
      float zbb[4] = {zb.x, zb.y, zb.z, zb.w};
#pragma unroll
      for (int i = 0; i < 4; i++) {
        float wv = W1[(LD + k4 * 4 + i) * HD + j];
        c1a += zaa[i] * wv;
        c1b += zbb[i] * wv;
      }
    }
  }
  const float w1t = W1[ZD * HD + j];   // time row
  const float b2j = b2[j];

  auto eval_f = [&](float t, const float (*src)[LD], float (*kout)[LD]) {
    __syncthreads();   // src (and previous-phase LDS reuse) ready
    // layer 1: h1[j] = tanh(c1 + t*w1t + vin @ W1[0:128])
    float a0 = c1a + t * w1t, a1 = c1b + t * w1t;
    {
      const float4* s0 = (const float4*)src[0];
      const float4* s1 = (const float4*)src[1];
#pragma unroll 8
      for (int k4 = 0; k4 < LD / 4; k4++) {
        float4 va = s0[k4], vb = s1[k4];
        float vaa[4] = {va.x, va.y, va.z, va.w};
        float vbb[4] = {vb.x, vb.y, vb.z, vb.w};
#pragma unroll
        for (int i = 0; i < 4; i++) {
          float wv = W1[(k4 * 4 + i) * HD + j];
          a0 += vaa[i] * wv;
          a1 += vbb[i] * wv;
        }
      }
    }
    hA[0][j] = fast_tanh(a0);
    hA[1][j] = fast_tanh(a1);
    __syncthreads();
    // layer 2: h2[j] = tanh(b2 + h1 @ W2)
    float g0 = b2j, g1 = b2j;
    {
      const float4* h0 = (const float4*)hA[0];
      const float4* h1 = (const float4*)hA[1];
#pragma unroll 8
      for (int k4 = 0; k4 < HD / 4; k4++) {
        float4 va = h0[k4], vb = h1[k4];
        float vaa[4] = {va.x, va.y, va.z, va.w};
        float vbb[4] = {vb.x, vb.y, vb.z, vb.w};
#pragma unroll
        for (int i = 0; i < 4; i++) {
          float wv = W2[(k4 * 4 + i) * HD + j];
          g0 += vaa[i] * wv;
          g1 += vbb[i] * wv;
        }
      }
    }
    hB[0][j] = fast_tanh(g0);
    hB[1][j] = fast_tanh(g1);
    __syncthreads();
    // layer 3: dL[u] = b3 + h2 @ W3 ; split-K across thread halves
    {
      const int u = j & (LD - 1), s = j >> 7;   // s = k-half
      float d0 = 0.f, d1 = 0.f;
      const float4* q0 = (const float4*)(hB[0] + s * 128);
      const float4* q1 = (const float4*)(hB[1] + s * 128);
#pragma unroll 8
      for (int k4 = 0; k4 < 32; k4++) {
        float4 va = q0[k4], vb = q1[k4];
        float vaa[4] = {va.x, va.y, va.z, va.w};
        float vbb[4] = {vb.x, vb.y, vb.z, vb.w};
#pragma unroll
        for (int i = 0; i < 4; i++) {
          float wv = W3[(s * 128 + k4 * 4 + i) * LD + u];
          d0 += vaa[i] * wv;
          d1 += vbb[i] * wv;
        }
      }
      p3[s][0][u] = d0;
      p3[s][1][u] = d1;
    }
    __syncthreads();
    if (j < LD) {
      kout[0][j] = p3[0][0][j] + p3[1][0][j] + b3[j];
      kout[1][j] = p3[0][1][j] + p3[1][1][j] + b3[j];
    }
  };

  eval_f(tv0, vLs, k1s);              // k1 = f(t0, vL)
  if (j < LD) {                       // same threads that wrote k1s
    vins[0][j] = vLs[0][j] + H * k1s[0][j];
    vins[1][j] = vLs[1][j] + H * k1s[1][j];
  }
  eval_f(tv1, vins, k2s);             // k2 = f(t1, vL + H*k1); starts w/ sync
  __syncthreads();

  // state write: 2 rows x 4 slots x 128 = 1024 floats, 4 per thread
#pragma unroll
  for (int it = 0; it < 4; it++) {
    int e = j + it * 256;
    int r = e >> 9, q = (e >> 7) & 3, k = e & 127;
    float val;
    if (q == 0)      val = vLs[r][k];
    else if (q == 1) val = k1s[r][k];
    else if (q == 2) val = vLs[r][k] + 0.5f * H * (k1s[r][k] + k2s[r][k]);
    else             val = k2s[r][k];   // predictor slope = Hermite right slope
    dstate[(size_t)(b0 + r) * 512 + q * 128 + k] = val;
  }
}

// ---------------------------------------------------------------------------
// Kernel 2: decode — register-resident B (packed in-register from raw Wh),
// m-tile loop. Block = (half, b): 512 blocks x 256 threads, 128 points each,
// both halves interpolating from the single macro-span state slice.
// zh[b] (z_ part GEMV) computed in-block, overlapped with Hermite.
// (verified R1/R2 form, unchanged)
// ---------------------------------------------------------------------------
__global__ __launch_bounds__(256, 2) void decode_kernel(
    const float* __restrict__ x, const float* __restrict__ x0,
    const float* __restrict__ dstate,
    const float* __restrict__ z, const float* __restrict__ Wh,
    const float* __restrict__ bh,
    const float* __restrict__ Wmu, const float* __restrict__ bmu,
    const float* __restrict__ Wsig, const float* __restrict__ bsig,
    float* __restrict__ out)
{
  const int b  = blockIdx.y;
  const int p0 = blockIdx.x * DPTS;   // half 0 or 1
  const int j  = threadIdx.x;

  __shared__ short latA[DPTS * 136];   // 128 points x 128 bf16 (+pad)
  __shared__ float sv4[4][LD];
  __shared__ float xv[DPTS];
  __shared__ float zr[LD];
  __shared__ float zhs[HD], wh0s[HD];
  __shared__ float wmus[384], wsgs[384];
  __shared__ float pmu[4][DPTS], psg[4][DPTS];

  const int w    = j >> 6;    // wave: n-tiles w*4 .. w*4+3 (units w*64..w*64+63)
  const int l    = j & 63;
  const int col  = l & 15;
  const int quad = l >> 4;

  for (int idx = j; idx < 512; idx += 256)
    sv4[idx >> 7][idx & 127] = dstate[(size_t)b * 512 + idx];
  if (j < DPTS) {
    xv[j] = x[b * P_SZ + p0 + j];
    zr[j] = z[b * ZD + LD + j];
  }
  wh0s[j] = Wh[j];
  for (int idx = j; idx < 384; idx += 256) {
    wmus[idx] = Wmu[idx];
    wsgs[idx] = Wsig[idx];
  }

  // B-fragments packed in-register from raw Wh f32 rows 1..128 (latent part);
  // no LDS dependency — loads issue here and complete under the Hermite phase.
  short8 Breg[4][4];
#pragma unroll
  for (int i = 0; i < 4; i++)
#pragma unroll
    for (int ks = 0; ks < 4; ks++)
      Breg[i][ks] = pack_bfrag(Wh + HD, HD, ks * 32 + quad * 8,
                               (w * 4 + i) * 16 + col);

  __syncthreads();

  // zh for this row: zhs[j] = bh[j] + z[b,128:] @ Wh[129:257]
  {
    float acc = bh[j];
#pragma unroll 8
    for (int k = 0; k < LD; k += 4) {
      float4 zv = *(const float4*)&zr[k];
      acc += zv.x * Wh[(LD + 1 + k) * HD + j] + zv.y * Wh[(LD + 2 + k) * HD + j]
           + zv.z * Wh[(LD + 3 + k) * HD + j] + zv.w * Wh[(LD + 4 + k) * HD + j];
    }
    zhs[j] = acc;
  }

  // Hermite over the single macro span [x0, x[255]]
  {
    const float t0 = x0[0];
    const float t1 = x[b * P_SZ + P_SZ - 1];
    const float H = t1 - t0, invH = 1.0f / H;
    unsigned int* latu = (unsigned int*)latA;   // row stride 68 uints
    for (int idx = j; idx < DPTS * 64; idx += 256) {
      int t = idx >> 6, kd = idx & 63;
      float s  = (xv[t] - t0) * invH;
      float s2 = s * s, s3 = s2 * s;
      float h00 = 2.f * s3 - 3.f * s2 + 1.f;
      float h10H = (s3 - 2.f * s2 + s) * H;
      float h01 = 3.f * s2 - 2.f * s3;
      float h11H = (s3 - s2) * H;
      float v0 = h00 * sv4[0][2 * kd]     + h10H * sv4[1][2 * kd]
               + h01 * sv4[2][2 * kd]     + h11H * sv4[3][2 * kd];
      float v1 = h00 * sv4[0][2 * kd + 1] + h10H * sv4[1][2 * kd + 1]
               + h01 * sv4[2][2 * kd + 1] + h11H * sv4[3][2 * kd + 1];
      latu[t * 68 + kd] = bf_bits(v0) | (bf_bits(v1) << 16);
    }
  }
  __syncthreads();

  float wh0r[4], zhr[4], wmur[4], wsgr[4];
#pragma unroll
  for (int i = 0; i < 4; i++) {
    int u = w * 64 + i * 16 + col;
    wh0r[i] = wh0s[u]; zhr[i] = zhs[u];
    wmur[i] = wmus[LD + u]; wsgr[i] = wsgs[LD + u];
  }
  float wml[8], wsl[8];
#pragma unroll
  for (int q = 0; q < 8; q++) {
    wml[q] = wmus[col * 8 + q];
    wsl[q] = wsgs[col * 8 + q];
  }

  for (int mt = 0; mt < DPTS / 16; mt++) {   // 8 m-tiles of 16 points
    short8 af[4];
#pragma unroll
    for (int ks = 0; ks < 4; ks++)
      af[ks] = *(const short8*)&latA[(mt * 16 + col) * 136 + ks * 32 + quad * 8];
    v4f acc[4];
#pragma unroll
    for (int i = 0; i < 4; i++) acc[i] = (v4f){0.f, 0.f, 0.f, 0.f};
#pragma unroll
    for (int i = 0; i < 4; i++)
#pragma unroll
      for (int ks = 0; ks < 4; ks++)
        acc[i] = __builtin_amdgcn_mfma_f32_16x16x32_bf16(
            af[ks], Breg[i][ks], acc[i], 0, 0, 0);

    float m4[4] = {0.f, 0.f, 0.f, 0.f}, s4[4] = {0.f, 0.f, 0.f, 0.f};
    float xr[4];
#pragma unroll
    for (int r = 0; r < 4; r++) xr[r] = xv[mt * 16 + quad * 4 + r];
#pragma unroll
    for (int i = 0; i < 4; i++)
#pragma unroll
      for (int r = 0; r < 4; r++) {
        float h = fmaxf(acc[i][r] + xr[r] * wh0r[i] + zhr[i], 0.f);
        m4[r] += h * wmur[i];
        s4[r] += h * wsgr[i];
      }
    if (w == 0) {   // latent-direct term added exactly once
#pragma unroll
      for (int r = 0; r < 4; r++) {
        int t = mt * 16 + quad * 4 + r;
        uint4 lw = *(const uint4*)&latA[t * 136 + col * 8];
        float l0 = bf_lo(lw.x), l1 = bf_hi(lw.x), l2 = bf_lo(lw.y), l3 = bf_hi(lw.y);
        float l4 = bf_lo(lw.z), l5 = bf_hi(lw.z), l6 = bf_lo(lw.w), l7 = bf_hi(lw.w);
        m4[r] += l0 * wml[0] + l1 * wml[1] + l2 * wml[2] + l3 * wml[3]
               + l4 * wml[4] + l5 * wml[5] + l6 * wml[6] + l7 * wml[7];
        s4[r] += l0 * wsl[0] + l1 * wsl[1] + l2 * wsl[2] + l3 * wsl[3]
               + l4 * wsl[4] + l5 * wsl[5] + l6 * wsl[6] + l7 * wsl[7];
      }
    }
#pragma unroll
    for (int r = 0; r < 4; r++) {
#pragma unroll
      for (int m = 1; m <= 8; m <<= 1) {
        m4[r] += __shfl_xor(m4[r], m);
        s4[r] += __shfl_xor(s4[r], m);
      }
    }
    if (col == 0) {
#pragma unroll
      for (int r = 0; r < 4; r++) {
        int t = mt * 16 + quad * 4 + r;
        pmu[w][t] = m4[r];
        psg[w][t] = s4[r];
      }
    }
  }
  __syncthreads();

  if (j < DPTS) {
    float m  = (pmu[0][j] + pmu[1][j]) + (pmu[2][j] + pmu[3][j]) + bmu[0];
    float sv = (psg[0][j] + psg[1][j]) + (psg[2][j] + psg[3][j]) + bsig[0];
    out[(size_t)b * P_SZ + p0 + j] = m;
    float sp = (sv > 20.f) ? sv : log1pf(__expf(sv));
    out[(size_t)B_SZ * P_SZ + b * P_SZ + p0 + j] = 0.1f + 0.9f * sp;
  }
}

// ---------------------------------------------------------------------------
extern "C" void kernel_launch(void* const* d_in, const int* in_sizes, int n_in,
                              void* d_out, int out_size, void* d_ws, size_t ws_size,
                              hipStream_t stream) {
  const float* x    = (const float*)d_in[0];
  const float* z    = (const float*)d_in[1];
  const float* x0   = (const float*)d_in[2];
  const float* W1   = (const float*)d_in[3];
  const float* b1   = (const float*)d_in[4];
  const float* W2   = (const float*)d_in[5];
  const float* b2   = (const float*)d_in[6];
  const float* W3   = (const float*)d_in[7];
  const float* b3   = (const float*)d_in[8];
  const float* Wh   = (const float*)d_in[9];
  const float* bh   = (const float*)d_in[10];
  const float* Wmu  = (const float*)d_in[11];
  const float* bmu  = (const float*)d_in[12];
  const float* Wsig = (const float*)d_in[13];
  const float* bsig = (const float*)d_in[14];
  float* out = (float*)d_out;

  char* ws = (char*)d_ws;
  float* dstate = (float*)ws;                      // 512 KB: [256][4][128] f32

  ode_gemv_kernel<<<dim3(B_SZ / 2), dim3(256), 0, stream>>>(
      x, z, x0, W1, b1, W2, b2, W3, b3, dstate);
  decode_kernel<<<dim3(P_SZ / DPTS, B_SZ), dim3(256), 0, stream>>>(
      x, x0, dstate, z, Wh, bh, Wmu, bmu, Wsig, bsig, out);
}

// Round 4
// 120.345 us; speedup vs baseline: 1.1679x; 1.1679x over previous
//
#include <hip/hip_runtime.h>
#include <hip/hip_bf16.h>
#include <math.h>

// Problem dims (fixed by reference)
#define B_SZ 256
#define P_SZ 256
#define LD   128   // L_DIM (evolving part)
#define ZD   256   // Z_DIM
#define HD   256   // H_DIM
#define DPTS 128   // points per decode block (2 blocks per row)
// Integrator: single Heun step over [x0, x[255]], 2 MLP evals total; the
// Hermite right slope is k2 = f(t1, vL+H*k1) (predictor slope). ODE in f32
// (more accurate than bf16-MFMA path); absmax floor remains the bf16 latent
// quantization in decode (0.0078125).
//
// R4: R3's GEMV died of latency (1 wave/SIMD, 640 scalar loads, 68 VGPR).
// GEMV-v2: 64 blocks x 1024 thr (4 waves/SIMD), float4 weight loads
// (wave-k-slice x lane-n-slice), 4 batch rows per block amortizing each
// load over 16 FLOP, split-K partials reduced through a 64 KB LDS buffer.
// launch_bounds(1024,4) opens 128 VGPRs for deep load pipelining.
// No pack kernel, 2 launches total. Decode = verified R2/R3 form.

typedef __attribute__((ext_vector_type(8))) short short8;   // 8 bf16 = 4 VGPRs
typedef __attribute__((ext_vector_type(4))) float v4f;      // mfma C/D

__device__ __forceinline__ float fast_tanh(float v) {
  float e = __expf(2.0f * fabsf(v));
  float r = 1.0f - 2.0f / (e + 1.0f);
  return copysignf(r, v);
}

__device__ __forceinline__ unsigned int bf_bits(float f) {
  unsigned int u = __float_as_uint(f);
  return (u + 0x7fffu + ((u >> 16) & 1u)) >> 16;   // RNE
}
__device__ __forceinline__ float bf_lo(unsigned int u) {
  return __uint_as_float(u << 16);
}
__device__ __forceinline__ float bf_hi(unsigned int u) {
  return __uint_as_float(u & 0xffff0000u);
}

// Build one MFMA B-fragment in lane order: lane (col,quad) holds
// B[k = kb..kb+7][n], kb = ks*32 + quad*8, as 8 bf16 (RNE from f32).
__device__ __forceinline__ short8 pack_bfrag(const float* __restrict__ W,
                                             int stride, int kb, int n) {
  short8 r;
#pragma unroll
  for (int j = 0; j < 8; j++)
    r[j] = (short)bf_bits(W[(kb + j) * stride + n]);
  return r;
}

// ---------------------------------------------------------------------------
// Kernel 1: GEMV-v2 ODE, Heun (2 evals), all f32.
// 64 blocks x 1024 threads (16 waves); block owns batch rows b0..b0+3.
// Layer partials: wave wv covers a k-slice, lane covers n-slice via float4
// weight loads shared across 4 rows; partials [wslice][row][n] in LDS,
// reduced by (row,n)-mapped threads. dstate layout identical to prior rounds.
// ---------------------------------------------------------------------------
__global__ __launch_bounds__(1024, 4) void ode_gemv2_kernel(
    const float* __restrict__ x, const float* __restrict__ z,
    const float* __restrict__ x0,
    const float* __restrict__ W1, const float* __restrict__ b1,
    const float* __restrict__ W2, const float* __restrict__ b2,
    const float* __restrict__ W3, const float* __restrict__ b3,
    float* __restrict__ dstate)   // [256 rows][4][128] f32
{
  __shared__ __align__(16) float part[16384];            // 64 KB
  __shared__ __align__(16) float vLs[4][LD], zfs[4][LD], vins[4][LD];
  __shared__ __align__(16) float c1s[4][HD], h1s[4][HD], h2s[4][HD];
  __shared__ __align__(16) float k1s[4][LD], k2s[4][LD];
  __shared__ float b1s[HD], w1ts[HD], b2s[HD], b3s[LD];

  const int t  = threadIdx.x;
  const int wv = t >> 6, l = t & 63;
  const int n4 = l * 4;                 // 256-wide layers: lane n-base
  const int b0 = blockIdx.x * 4;

  // ---- stage: 4 z rows (1 float/thread), biases, time row ----
  {
    int r = t >> 8, c = t & 255;
    float v = z[(b0 + r) * ZD + c];
    if (c < LD) vLs[r][c] = v; else zfs[r][c - LD] = v;
  }
  if (t < HD) {
    b1s[t]  = b1[t];
    w1ts[t] = W1[ZD * HD + t];
    b2s[t]  = b2[t];
  }
  if (t < LD) b3s[t] = b3[t];
  const float tv0 = x0[0];
  const float tv1 = x[P_SZ - 1];
  const float H   = tv1 - tv0;
  __syncthreads();

  // K=128 -> N=256 partial: wave wv takes k in [krow0+8wv, +8)
  auto part128 = [&](const float (*src)[LD], const float* __restrict__ W,
                     int krow0) {
    float4 wv8[8];
#pragma unroll
    for (int kk = 0; kk < 8; kk++)
      wv8[kk] = *(const float4*)&W[(krow0 + wv * 8 + kk) * HD + n4];
    float sr[4][8];
#pragma unroll
    for (int r = 0; r < 4; r++) {
      float4 a = *(const float4*)&src[r][wv * 8];
      float4 b = *(const float4*)&src[r][wv * 8 + 4];
      sr[r][0]=a.x; sr[r][1]=a.y; sr[r][2]=a.z; sr[r][3]=a.w;
      sr[r][4]=b.x; sr[r][5]=b.y; sr[r][6]=b.z; sr[r][7]=b.w;
    }
#pragma unroll
    for (int r = 0; r < 4; r++) {
      float4 acc = (float4){0.f, 0.f, 0.f, 0.f};
#pragma unroll
      for (int kk = 0; kk < 8; kk++) {
        acc.x += sr[r][kk] * wv8[kk].x;
        acc.y += sr[r][kk] * wv8[kk].y;
        acc.z += sr[r][kk] * wv8[kk].z;
        acc.w += sr[r][kk] * wv8[kk].w;
      }
      *(float4*)&part[wv * 1024 + r * 256 + n4] = acc;
    }
  };

  // K=256 -> N=256 partial: wave wv takes k in [16wv, +16), two 8-chunks
  auto part256 = [&](const float (*src)[HD]) {
    float4 accv[4];
#pragma unroll
    for (int r = 0; r < 4; r++) accv[r] = (float4){0.f, 0.f, 0.f, 0.f};
#pragma unroll
    for (int ch = 0; ch < 2; ch++) {
      float4 wv8[8];
#pragma unroll
      for (int kk = 0; kk < 8; kk++)
        wv8[kk] = *(const float4*)&W2[(wv * 16 + ch * 8 + kk) * HD + n4];
      float sr[4][8];
#pragma unroll
      for (int r = 0; r < 4; r++) {
        float4 a = *(const float4*)&src[r][wv * 16 + ch * 8];
        float4 b = *(const float4*)&src[r][wv * 16 + ch * 8 + 4];
        sr[r][0]=a.x; sr[r][1]=a.y; sr[r][2]=a.z; sr[r][3]=a.w;
        sr[r][4]=b.x; sr[r][5]=b.y; sr[r][6]=b.z; sr[r][7]=b.w;
      }
#pragma unroll
      for (int r = 0; r < 4; r++)
#pragma unroll
        for (int kk = 0; kk < 8; kk++) {
          accv[r].x += sr[r][kk] * wv8[kk].x;
          accv[r].y += sr[r][kk] * wv8[kk].y;
          accv[r].z += sr[r][kk] * wv8[kk].z;
          accv[r].w += sr[r][kk] * wv8[kk].w;
        }
    }
#pragma unroll
    for (int r = 0; r < 4; r++)
      *(float4*)&part[wv * 1024 + r * 256 + n4] = accv[r];
  };

  // K=256 -> N=128 partial (W3): 32 k-slices, half-wave n-coverage
  auto part3 = [&](const float (*src)[HD]) {
    const int s  = wv * 2 + (l >> 5);   // k-slice 0..31, k in [8s, 8s+8)
    const int m4 = (l & 31) * 4;        // n-base 0..124
    float4 wv8[8];
#pragma unroll
    for (int kk = 0; kk < 8; kk++)
      wv8[kk] = *(const float4*)&W3[(s * 8 + kk) * LD + m4];
    float sr[4][8];
#pragma unroll
    for (int r = 0; r < 4; r++) {
      float4 a = *(const float4*)&src[r][s * 8];
      float4 b = *(const float4*)&src[r][s * 8 + 4];
      sr[r][0]=a.x; sr[r][1]=a.y; sr[r][2]=a.z; sr[r][3]=a.w;
      sr[r][4]=b.x; sr[r][5]=b.y; sr[r][6]=b.z; sr[r][7]=b.w;
    }
#pragma unroll
    for (int r = 0; r < 4; r++) {
      float4 acc = (float4){0.f, 0.f, 0.f, 0.f};
#pragma unroll
      for (int kk = 0; kk < 8; kk++) {
        acc.x += sr[r][kk] * wv8[kk].x;
        acc.y += sr[r][kk] * wv8[kk].y;
        acc.z += sr[r][kk] * wv8[kk].z;
        acc.w += sr[r][kk] * wv8[kk].w;
      }
      *(float4*)&part[s * 512 + r * 128 + m4] = acc;
    }
  };

  // reduce 16 wave-partials at (r,n) = (t>>8, t&255)
  auto red16 = [&]() -> float {
    int r = t >> 8, n = t & 255;
    float s = 0.f;
#pragma unroll
    for (int w8 = 0; w8 < 16; w8++) s += part[w8 * 1024 + r * 256 + n];
    return s;
  };

  // ---- c1 = b1 + zf @ W1[128:256] ----
  part128(zfs, W1, 128);
  __syncthreads();
  {
    int r = t >> 8, n = t & 255;
    c1s[r][n] = red16() + b1s[n];
  }
  __syncthreads();

  auto eval_f = [&](float tt, const float (*src)[LD], float (*kout)[LD]) {
    // layer 1
    part128(src, W1, 0);
    __syncthreads();
    {
      int r = t >> 8, n = t & 255;
      h1s[r][n] = fast_tanh(red16() + c1s[r][n] + tt * w1ts[n]);
    }
    __syncthreads();
    // layer 2
    part256(h1s);
    __syncthreads();
    {
      int r = t >> 8, n = t & 255;
      h2s[r][n] = fast_tanh(red16() + b2s[n]);
    }
    __syncthreads();
    // layer 3
    part3(h2s);
    __syncthreads();
    if (t < 512) {
      int r = t >> 7, n = t & 127;
      float s = 0.f;
#pragma unroll
      for (int ss = 0; ss < 32; ss++) s += part[ss * 512 + r * 128 + n];
      kout[r][n] = s + b3s[n];
    }
    __syncthreads();
  };

  eval_f(tv0, vLs, k1s);              // k1 = f(t0, vL)
  if (t < 512) {
    int r = t >> 7, n = t & 127;
    vins[r][n] = vLs[r][n] + H * k1s[r][n];
  }
  __syncthreads();
  eval_f(tv1, vins, k2s);             // k2 = f(t1, vL + H*k1)

  // state write: 4 rows x 4 slots x 128 = 2048 floats, 2 per thread
#pragma unroll
  for (int it = 0; it < 2; it++) {
    int e = t + it * 1024;
    int r = e >> 9, q = (e >> 7) & 3, k = e & 127;
    float val;
    if (q == 0)      val = vLs[r][k];
    else if (q == 1) val = k1s[r][k];
    else if (q == 2) val = vLs[r][k] + 0.5f * H * (k1s[r][k] + k2s[r][k]);
    else             val = k2s[r][k];   // predictor slope = Hermite right slope
    dstate[(size_t)(b0 + r) * 512 + q * 128 + k] = val;
  }
}

// ---------------------------------------------------------------------------
// Kernel 2: decode — register-resident B (packed in-register from raw Wh),
// m-tile loop. Block = (half, b): 512 blocks x 256 threads, 128 points each,
// both halves interpolating from the single macro-span state slice.
// zh[b] (z_ part GEMV) computed in-block, overlapped with Hermite.
// (verified R1/R2/R3 form, unchanged)
// ---------------------------------------------------------------------------
__global__ __launch_bounds__(256, 2) void decode_kernel(
    const float* __restrict__ x, const float* __restrict__ x0,
    const float* __restrict__ dstate,
    const float* __restrict__ z, const float* __restrict__ Wh,
    const float* __restrict__ bh,
    const float* __restrict__ Wmu, const float* __restrict__ bmu,
    const float* __restrict__ Wsig, const float* __restrict__ bsig,
    float* __restrict__ out)
{
  const int b  = blockIdx.y;
  const int p0 = blockIdx.x * DPTS;   // half 0 or 1
  const int j  = threadIdx.x;

  __shared__ short latA[DPTS * 136];   // 128 points x 128 bf16 (+pad)
  __shared__ float sv4[4][LD];
  __shared__ float xv[DPTS];
  __shared__ float zr[LD];
  __shared__ float zhs[HD], wh0s[HD];
  __shared__ float wmus[384], wsgs[384];
  __shared__ float pmu[4][DPTS], psg[4][DPTS];

  const int w    = j >> 6;    // wave: n-tiles w*4 .. w*4+3 (units w*64..w*64+63)
  const int l    = j & 63;
  const int col  = l & 15;
  const int quad = l >> 4;

  for (int idx = j; idx < 512; idx += 256)
    sv4[idx >> 7][idx & 127] = dstate[(size_t)b * 512 + idx];
  if (j < DPTS) {
    xv[j] = x[b * P_SZ + p0 + j];
    zr[j] = z[b * ZD + LD + j];
  }
  wh0s[j] = Wh[j];
  for (int idx = j; idx < 384; idx += 256) {
    wmus[idx] = Wmu[idx];
    wsgs[idx] = Wsig[idx];
  }

  // B-fragments packed in-register from raw Wh f32 rows 1..128 (latent part);
  // no LDS dependency — loads issue here and complete under the Hermite phase.
  short8 Breg[4][4];
#pragma unroll
  for (int i = 0; i < 4; i++)
#pragma unroll
    for (int ks = 0; ks < 4; ks++)
      Breg[i][ks] = pack_bfrag(Wh + HD, HD, ks * 32 + quad * 8,
                               (w * 4 + i) * 16 + col);

  __syncthreads();

  // zh for this row: zhs[j] = bh[j] + z[b,128:] @ Wh[129:257]
  {
    float acc = bh[j];
#pragma unroll 8
    for (int k = 0; k < LD; k += 4) {
      float4 zv = *(const float4*)&zr[k];
      acc += zv.x * Wh[(LD + 1 + k) * HD + j] + zv.y * Wh[(LD + 2 + k) * HD + j]
           + zv.z * Wh[(LD + 3 + k) * HD + j] + zv.w * Wh[(LD + 4 + k) * HD + j];
    }
    zhs[j] = acc;
  }

  // Hermite over the single macro span [x0, x[255]]
  {
    const float t0 = x0[0];
    const float t1 = x[b * P_SZ + P_SZ - 1];
    const float H = t1 - t0, invH = 1.0f / H;
    unsigned int* latu = (unsigned int*)latA;   // row stride 68 uints
    for (int idx = j; idx < DPTS * 64; idx += 256) {
      int t = idx >> 6, kd = idx & 63;
      float s  = (xv[t] - t0) * invH;
      float s2 = s * s, s3 = s2 * s;
      float h00 = 2.f * s3 - 3.f * s2 + 1.f;
      float h10H = (s3 - 2.f * s2 + s) * H;
      float h01 = 3.f * s2 - 2.f * s3;
      float h11H = (s3 - s2) * H;
      float v0 = h00 * sv4[0][2 * kd]     + h10H * sv4[1][2 * kd]
               + h01 * sv4[2][2 * kd]     + h11H * sv4[3][2 * kd];
      float v1 = h00 * sv4[0][2 * kd + 1] + h10H * sv4[1][2 * kd + 1]
               + h01 * sv4[2][2 * kd + 1] + h11H * sv4[3][2 * kd + 1];
      latu[t * 68 + kd] = bf_bits(v0) | (bf_bits(v1) << 16);
    }
  }
  __syncthreads();

  float wh0r[4], zhr[4], wmur[4], wsgr[4];
#pragma unroll
  for (int i = 0; i < 4; i++) {
    int u = w * 64 + i * 16 + col;
    wh0r[i] = wh0s[u]; zhr[i] = zhs[u];
    wmur[i] = wmus[LD + u]; wsgr[i] = wsgs[LD + u];
  }
  float wml[8], wsl[8];
#pragma unroll
  for (int q = 0; q < 8; q++) {
    wml[q] = wmus[col * 8 + q];
    wsl[q] = wsgs[col * 8 + q];
  }

  for (int mt = 0; mt < DPTS / 16; mt++) {   // 8 m-tiles of 16 points
    short8 af[4];
#pragma unroll
    for (int ks = 0; ks < 4; ks++)
      af[ks] = *(const short8*)&latA[(mt * 16 + col) * 136 + ks * 32 + quad * 8];
    v4f acc[4];
#pragma unroll
    for (int i = 0; i < 4; i++) acc[i] = (v4f){0.f, 0.f, 0.f, 0.f};
#pragma unroll
    for (int i = 0; i < 4; i++)
#pragma unroll
      for (int ks = 0; ks < 4; ks++)
        acc[i] = __builtin_amdgcn_mfma_f32_16x16x32_bf16(
            af[ks], Breg[i][ks], acc[i], 0, 0, 0);

    float m4[4] = {0.f, 0.f, 0.f, 0.f}, s4[4] = {0.f, 0.f, 0.f, 0.f};
    float xr[4];
#pragma unroll
    for (int r = 0; r < 4; r++) xr[r] = xv[mt * 16 + quad * 4 + r];
#pragma unroll
    for (int i = 0; i < 4; i++)
#pragma unroll
      for (int r = 0; r < 4; r++) {
        float h = fmaxf(acc[i][r] + xr[r] * wh0r[i] + zhr[i], 0.f);
        m4[r] += h * wmur[i];
        s4[r] += h * wsgr[i];
      }
    if (w == 0) {   // latent-direct term added exactly once
#pragma unroll
      for (int r = 0; r < 4; r++) {
        int t = mt * 16 + quad * 4 + r;
        uint4 lw = *(const uint4*)&latA[t * 136 + col * 8];
        float l0 = bf_lo(lw.x), l1 = bf_hi(lw.x), l2 = bf_lo(lw.y), l3 = bf_hi(lw.y);
        float l4 = bf_lo(lw.z), l5 = bf_hi(lw.z), l6 = bf_lo(lw.w), l7 = bf_hi(lw.w);
        m4[r] += l0 * wml[0] + l1 * wml[1] + l2 * wml[2] + l3 * wml[3]
               + l4 * wml[4] + l5 * wml[5] + l6 * wml[6] + l7 * wml[7];
        s4[r] += l0 * wsl[0] + l1 * wsl[1] + l2 * wsl[2] + l3 * wsl[3]
               + l4 * wsl[4] + l5 * wsl[5] + l6 * wsl[6] + l7 * wsl[7];
      }
    }
#pragma unroll
    for (int r = 0; r < 4; r++) {
#pragma unroll
      for (int m = 1; m <= 8; m <<= 1) {
        m4[r] += __shfl_xor(m4[r], m);
        s4[r] += __shfl_xor(s4[r], m);
      }
    }
    if (col == 0) {
#pragma unroll
      for (int r = 0; r < 4; r++) {
        int t = mt * 16 + quad * 4 + r;
        pmu[w][t] = m4[r];
        psg[w][t] = s4[r];
      }
    }
  }
  __syncthreads();

  if (j < DPTS) {
    float m  = (pmu[0][j] + pmu[1][j]) + (pmu[2][j] + pmu[3][j]) + bmu[0];
    float sv = (psg[0][j] + psg[1][j]) + (psg[2][j] + psg[3][j]) + bsig[0];
    out[(size_t)b * P_SZ + p0 + j] = m;
    float sp = (sv > 20.f) ? sv : log1pf(__expf(sv));
    out[(size_t)B_SZ * P_SZ + b * P_SZ + p0 + j] = 0.1f + 0.9f * sp;
  }
}

// ---------------------------------------------------------------------------
extern "C" void kernel_launch(void* const* d_in, const int* in_sizes, int n_in,
                              void* d_out, int out_size, void* d_ws, size_t ws_size,
                              hipStream_t stream) {
  const float* x    = (const float*)d_in[0];
  const float* z    = (const float*)d_in[1];
  const float* x0   = (const float*)d_in[2];
  const float* W1   = (const float*)d_in[3];
  const float* b1   = (const float*)d_in[4];
  const float* W2   = (const float*)d_in[5];
  const float* b2   = (const float*)d_in[6];
  const float* W3   = (const float*)d_in[7];
  const float* b3   = (const float*)d_in[8];
  const float* Wh   = (const float*)d_in[9];
  const float* bh   = (const float*)d_in[10];
  const float* Wmu  = (const float*)d_in[11];
  const float* bmu  = (const float*)d_in[12];
  const float* Wsig = (const float*)d_in[13];
  const float* bsig = (const float*)d_in[14];
  float* out = (float*)d_out;

  char* ws = (char*)d_ws;
  float* dstate = (float*)ws;                      // 512 KB: [256][4][128] f32

  ode_gemv2_kernel<<<dim3(B_SZ / 4), dim3(1024), 0, stream>>>(
      x, z, x0, W1, b1, W2, b2, W3, b3, dstate);
  decode_kernel<<<dim3(P_SZ / DPTS, B_SZ), dim3(256), 0, stream>>>(
      x, x0, dstate, z, Wh, bh, Wmu, bmu, Wsig, bsig, out);
}